// Round 1
// baseline (715.070 us; speedup 1.0000x reference)
//
#include <hip/hip_runtime.h>
#include <hip/hip_bf16.h>
#include <stdint.h>

// QLoRA linear on MI355X (gfx950).
// Strategy: fold LoRA into weights (W_eff = q*s + 2*B@A), cast x and W_eff to
// bf16, run a single B^T-layout MFMA GEMM (m97 structure: 128x128 tile, BK=64,
// global_load_lds width=16, 2-barrier K-loop), bias fused into epilogue.

#define IN_F 4096
#define OUT_F 4096

typedef unsigned short u16;
typedef __attribute__((ext_vector_type(8))) short s16x8;
typedef __attribute__((ext_vector_type(4))) float f32x4;

__device__ inline u16 f2bf(float f) {
    union { float f; uint32_t u; } v; v.f = f;
    uint32_t u = v.u;
    // round-to-nearest-even fp32 -> bf16
    return (u16)((u + 0x7FFFu + ((u >> 16) & 1u)) >> 16);
}

// ---------------------------------------------------------------- cvt x -> bf16
__global__ __launch_bounds__(256) void cvt_x_kernel(const float* __restrict__ x,
                                                    u16* __restrict__ xb, int n8) {
    int t = blockIdx.x * 256 + threadIdx.x;
    if (t >= n8) return;
    const float4* src = (const float4*)x + (size_t)t * 2;
    float4 a = src[0], b = src[1];
    union { u16 u[8]; s16x8 v; } o;
    o.u[0] = f2bf(a.x); o.u[1] = f2bf(a.y); o.u[2] = f2bf(a.z); o.u[3] = f2bf(a.w);
    o.u[4] = f2bf(b.x); o.u[5] = f2bf(b.y); o.u[6] = f2bf(b.z); o.u[7] = f2bf(b.w);
    ((s16x8*)xb)[t] = o.v;
}

// ------------------------------------------- W_eff = q*s + 2*(B@A), cast to bf16
__global__ __launch_bounds__(256) void build_weff_kernel(const int* __restrict__ qw,
                                                         const float* __restrict__ qs,
                                                         const float* __restrict__ lA,
                                                         const float* __restrict__ lB,
                                                         u16* __restrict__ w) {
    int t = blockIdx.x * 256 + threadIdx.x;     // OUT_F*IN_F/8 threads
    int o  = t >> 9;                            // IN_F/8 = 512 threads per row
    int i0 = (t & 511) << 3;
    float s = qs[o];
    const int4* q4 = (const int4*)(qw + (size_t)o * IN_F + i0);
    int4 qa = q4[0], qb = q4[1];
    float acc[8];
    acc[0] = qa.x * s; acc[1] = qa.y * s; acc[2] = qa.z * s; acc[3] = qa.w * s;
    acc[4] = qb.x * s; acc[5] = qb.y * s; acc[6] = qb.z * s; acc[7] = qb.w * s;
#pragma unroll
    for (int r = 0; r < 16; ++r) {
        float br = 2.0f * lB[o * 16 + r];       // SCALING = 2.0
        const float4* a4 = (const float4*)(lA + (size_t)r * IN_F + i0);
        float4 aa = a4[0], ab = a4[1];
        acc[0] += br * aa.x; acc[1] += br * aa.y; acc[2] += br * aa.z; acc[3] += br * aa.w;
        acc[4] += br * ab.x; acc[5] += br * ab.y; acc[6] += br * ab.z; acc[7] += br * ab.w;
    }
    union { u16 u[8]; s16x8 v; } ov;
#pragma unroll
    for (int j = 0; j < 8; ++j) ov.u[j] = f2bf(acc[j]);
    ((s16x8*)w)[t] = ov.v;
}

// ---------------------------------------------------------------- bf16 GEMM B^T
// out[m][n] = sum_k Xb[m][k] * Wb[n][k] + bias[n]
#define BM 128
#define BN 128
#define BK 64

#define GLD16(gp, lp)                                                          \
    __builtin_amdgcn_global_load_lds(                                          \
        (const __attribute__((address_space(1))) void*)(gp),                   \
        (__attribute__((address_space(3))) void*)(lp), 16, 0, 0)

__global__ __launch_bounds__(256) void gemm_bt_kernel(const short* __restrict__ Xb,
                                                      const short* __restrict__ Wb,
                                                      const float* __restrict__ bias,
                                                      float* __restrict__ out) {
    __shared__ __align__(16) short lA[BM * BK];   // 16 KB, linear (gld_lds dest)
    __shared__ __align__(16) short lB[BN * BK];   // 16 KB

    const int tid  = threadIdx.x;
    const int wave = tid >> 6, lane = tid & 63;
    const int m0 = blockIdx.y * BM;
    const int n0 = blockIdx.x * BN;
    const int wr = (wave >> 1) * 64;              // wave row offset in tile
    const int wc = (wave & 1) * 64;               // wave col offset in tile

    f32x4 zero = {0.f, 0.f, 0.f, 0.f};
    f32x4 acc[4][4];
#pragma unroll
    for (int i = 0; i < 4; ++i)
#pragma unroll
        for (int j = 0; j < 4; ++j) acc[i][j] = zero;

    // staging coords: chunk = 1024B = 8 rows of 128B; lane l -> row l/8, col (l%8)*8
    const int sr = lane >> 3;
    const int sc = (lane & 7) * 8;

    const short* gA = Xb + (size_t)m0 * IN_F;
    const short* gB = Wb + (size_t)n0 * IN_F;

    for (int kt = 0; kt < IN_F; kt += BK) {
#pragma unroll
        for (int j = 0; j < 4; ++j) {
            int chunk = wave * 4 + j;             // 0..15
            int r = chunk * 8 + sr;               // 0..127
            GLD16(gA + (size_t)r * IN_F + kt + sc, (char*)lA + chunk * 1024);
            GLD16(gB + (size_t)r * IN_F + kt + sc, (char*)lB + chunk * 1024);
        }
        __syncthreads();   // compiler emits vmcnt(0) drain before barrier

#pragma unroll
        for (int kk = 0; kk < 2; ++kk) {
            const int ko   = kk * 32 + (lane >> 4) * 8;  // k offset of this lane's 8 elems
            const int rsel = lane & 15;                  // row/col within fragment
            s16x8 af[4], bf[4];
#pragma unroll
            for (int mi = 0; mi < 4; ++mi)
                af[mi] = *(const s16x8*)&lA[(wr + mi * 16 + rsel) * BK + ko];
#pragma unroll
            for (int ni = 0; ni < 4; ++ni)
                bf[ni] = *(const s16x8*)&lB[(wc + ni * 16 + rsel) * BK + ko];
#pragma unroll
            for (int mi = 0; mi < 4; ++mi)
#pragma unroll
                for (int ni = 0; ni < 4; ++ni)
                    acc[mi][ni] = __builtin_amdgcn_mfma_f32_16x16x32_bf16(
                        af[mi], bf[ni], acc[mi][ni], 0, 0, 0);
        }
        __syncthreads();
    }

    // epilogue: C/D layout col = lane&15, row = (lane>>4)*4 + reg  [m89-verified]
    const int col = lane & 15, rq = (lane >> 4) * 4;
#pragma unroll
    for (int ni = 0; ni < 4; ++ni) {
        int gn = n0 + wc + ni * 16 + col;
        float bv = bias[gn];
#pragma unroll
        for (int mi = 0; mi < 4; ++mi) {
            int gm = m0 + wr + mi * 16 + rq;
#pragma unroll
            for (int r = 0; r < 4; ++r)
                out[(size_t)(gm + r) * OUT_F + gn] = acc[mi][ni][r] + bv;
        }
    }
}

extern "C" void kernel_launch(void* const* d_in, const int* in_sizes, int n_in,
                              void* d_out, int out_size, void* d_ws, size_t ws_size,
                              hipStream_t stream) {
    const float* x    = (const float*)d_in[0];
    const int*   qw   = (const int*)d_in[1];
    const float* qs   = (const float*)d_in[2];
    const float* bias = (const float*)d_in[3];
    const float* lA   = (const float*)d_in[4];
    const float* lB   = (const float*)d_in[5];
    float* out = (float*)d_out;

    const int xN = in_sizes[0];          // M * IN_F
    const int M  = xN / IN_F;            // 8192

    // workspace: [x_bf16: xN shorts][W_eff: OUT_F*IN_F shorts] = ~100 MB
    short* xb = (short*)d_ws;
    short* wb = xb + (size_t)xN;

    const int n8 = xN / 8;
    hipLaunchKernelGGL(cvt_x_kernel, dim3(n8 / 256), dim3(256), 0, stream,
                       x, (u16*)xb, n8);
    hipLaunchKernelGGL(build_weff_kernel, dim3((OUT_F * (IN_F / 8)) / 256), dim3(256),
                       0, stream, qw, qs, lA, lB, (u16*)wb);
    hipLaunchKernelGGL(gemm_bt_kernel, dim3(OUT_F / BN, M / BM), dim3(256), 0, stream,
                       xb, wb, bias, out);
}

// Round 2
// 568.270 us; speedup vs baseline: 1.2583x; 1.2583x over previous
//
#include <hip/hip_runtime.h>
#include <hip/hip_bf16.h>
#include <stdint.h>

// QLoRA linear on MI355X (gfx950).
// W_eff = dequant(q)*s + 2*B@A folded once; x cast to bf16; single bf16 GEMM.
// GEMM: 256x256 tile, BK=32, 8 waves (2Mx4N), 4 LDS buffers (128 KiB),
// 2-phase/K-tile schedule with counted vmcnt(8), T2 XOR-swizzle (both-sides),
// T5 setprio, T1 XCD block swizzle. Bias fused in epilogue.

#define IN_F 4096
#define OUT_F 4096

typedef unsigned short u16;
typedef __attribute__((ext_vector_type(8))) short s16x8;
typedef __attribute__((ext_vector_type(4))) float f32x4;

__device__ inline u16 f2bf(float f) {
    union { float f; uint32_t u; } v; v.f = f;
    uint32_t u = v.u;
    return (u16)((u + 0x7FFFu + ((u >> 16) & 1u)) >> 16);   // RNE fp32->bf16
}

// ---------------------------------------------------------------- cvt x -> bf16
__global__ __launch_bounds__(256) void cvt_x_kernel(const float* __restrict__ x,
                                                    u16* __restrict__ xb, int n8) {
    int t = blockIdx.x * 256 + threadIdx.x;
    if (t >= n8) return;
    const float4* src = (const float4*)x + (size_t)t * 2;
    float4 a = src[0], b = src[1];
    union { u16 u[8]; s16x8 v; } o;
    o.u[0] = f2bf(a.x); o.u[1] = f2bf(a.y); o.u[2] = f2bf(a.z); o.u[3] = f2bf(a.w);
    o.u[4] = f2bf(b.x); o.u[5] = f2bf(b.y); o.u[6] = f2bf(b.z); o.u[7] = f2bf(b.w);
    ((s16x8*)xb)[t] = o.v;
}

// ------------------------------------------- W_eff = q*s + 2*(B@A), cast to bf16
__global__ __launch_bounds__(256) void build_weff_kernel(const int* __restrict__ qw,
                                                         const float* __restrict__ qs,
                                                         const float* __restrict__ lA,
                                                         const float* __restrict__ lB,
                                                         u16* __restrict__ w) {
    int t = blockIdx.x * 256 + threadIdx.x;     // OUT_F*IN_F/8 threads
    int o  = t >> 9;                            // 512 threads per row
    int i0 = (t & 511) << 3;
    float s = qs[o];
    const int4* q4 = (const int4*)(qw + (size_t)o * IN_F + i0);
    int4 qa = q4[0], qb = q4[1];
    float acc[8];
    acc[0] = qa.x * s; acc[1] = qa.y * s; acc[2] = qa.z * s; acc[3] = qa.w * s;
    acc[4] = qb.x * s; acc[5] = qb.y * s; acc[6] = qb.z * s; acc[7] = qb.w * s;
#pragma unroll
    for (int r = 0; r < 16; ++r) {
        float br = 2.0f * lB[o * 16 + r];       // SCALING = 2.0
        const float4* a4 = (const float4*)(lA + (size_t)r * IN_F + i0);
        float4 aa = a4[0], ab = a4[1];
        acc[0] += br * aa.x; acc[1] += br * aa.y; acc[2] += br * aa.z; acc[3] += br * aa.w;
        acc[4] += br * ab.x; acc[5] += br * ab.y; acc[6] += br * ab.z; acc[7] += br * ab.w;
    }
    union { u16 u[8]; s16x8 v; } ov;
#pragma unroll
    for (int j = 0; j < 8; ++j) ov.u[j] = f2bf(acc[j]);
    ((s16x8*)w)[t] = ov.v;
}

// ---------------------------------------------------------------- bf16 GEMM B^T
// out[m][n] = sum_k Xb[m][k] * Wb[n][k] + bias[n]
#define BK 32
#define NT (IN_F / BK)     // 128 K-tiles

#define GLD16(gp, lp)                                                          \
    __builtin_amdgcn_global_load_lds(                                          \
        (const __attribute__((address_space(1))) void*)(gp),                   \
        (__attribute__((address_space(3))) void*)(lp), 16, 0, 0)

__global__ __launch_bounds__(512, 2) void gemm_bt_kernel(const short* __restrict__ Xb,
                                                         const short* __restrict__ Wb,
                                                         const float* __restrict__ bias,
                                                         float* __restrict__ out,
                                                         int nmt) {
    // A: 4 bufs x [256][32] bf16 = 64 KB at [0,65536); B same at [65536,131072)
    __shared__ __align__(16) char smem[131072];

    const int tid  = threadIdx.x;
    const int w    = tid >> 6, lane = tid & 63;
    const int wm   = w >> 2, wn = w & 3;        // 2M x 4N wave grid
    const int rl   = lane & 15;

    // T1: bijective XCD swizzle (nwg % 8 == 0)
    const int nwg = nmt * 16;                   // N/256 = 16 n-tiles
    const int cpx = nwg >> 3;
    const int f   = blockIdx.x;
    const int swz = (f & 7) * cpx + (f >> 3);
    const int m0  = (swz >> 4) * 256;
    const int n0  = (swz & 15) * 256;

    // ---- staging source coords (T2: linear LDS dest, inverse-swizzled source)
    // linear byte L in a 16KB tile = j*8192 + w*1024 + lane*16; swz flips bits 4-5
    // by (L>>7)&3 = (lane>>3)&3 (chunk/wave bits drop out mod 4).
    const int L0   = w * 1024 + lane * 16;
    const int S0   = L0 ^ (((lane >> 3) & 3) << 4);
    const int srow = S0 >> 6;                   // 0..127
    const int scol = (S0 & 63) >> 1;            // shorts, in {0,8,16,24}
    const short* pA = Xb + (size_t)(m0 + srow) * IN_F + scol;
    const short* pB = Wb + (size_t)(n0 + srow) * IN_F + scol;
    char* ldsA = (char*)smem;
    char* ldsB = (char*)smem + 65536;
    const int woff = w * 1024;

#define STAGE_A(t) do { int bo_ = ((t) & 3) * 16384 + woff;                    \
        const short* s_ = pA + (size_t)(t) * BK;                               \
        GLD16(s_, ldsA + bo_);                                                 \
        GLD16(s_ + (size_t)128 * IN_F, ldsA + bo_ + 8192); } while (0)
#define STAGE_B(t) do { int bo_ = ((t) & 3) * 16384 + woff;                    \
        const short* s_ = pB + (size_t)(t) * BK;                               \
        GLD16(s_, ldsB + bo_);                                                 \
        GLD16(s_ + (size_t)128 * IN_F, ldsB + bo_ + 8192); } while (0)

    // ---- ds_read addressing: tile byte T = row*64 + (lane>>4)*16, read at
    // swz(T); XOR term = ((rl>>1)&3)<<4 is lane-constant (row bits 1-2 come
    // from rl only, since wave/mi offsets are multiples of 8 in row>>1).
    const int colpart = ((lane >> 4) * 16) ^ (((rl >> 1) & 3) << 4);
    const int aRow = (wm * 128 + rl) * 64 + colpart;
    const int bRow = (wn * 64 + rl) * 64 + colpart;

    f32x4 acc[8][4];
    f32x4 zero = {0.f, 0.f, 0.f, 0.f};
#pragma unroll
    for (int i = 0; i < 8; ++i)
#pragma unroll
        for (int j = 0; j < 4; ++j) acc[i][j] = zero;

    // prologue: prefetch tiles 0,1,2; need tile 0 landed (newest 8 = tiles 1,2)
    STAGE_A(0); STAGE_B(0); STAGE_A(1); STAGE_B(1); STAGE_A(2); STAGE_B(2);
    asm volatile("s_waitcnt vmcnt(8)" ::: "memory");
    __builtin_amdgcn_s_barrier();

    for (int t = 0; t < NT; ++t) {
        const char* aB = ldsA + (t & 3) * 16384 + aRow;
        const char* bB = ldsB + (t & 3) * 16384 + bRow;
        s16x8 a[8], b0, b1, b2, b3;

        // ---- phase 0: quadrant ni 0-1 (A frags live across both phases)
#pragma unroll
        for (int mi = 0; mi < 8; ++mi) a[mi] = *(const s16x8*)(aB + mi * 1024);
        b0 = *(const s16x8*)(bB);
        b1 = *(const s16x8*)(bB + 1024);
        if (t < NT - 3) STAGE_A(t + 3);        // buf (t-1)&3: readers done >=2 barriers ago
        __builtin_amdgcn_s_barrier();
        __builtin_amdgcn_s_setprio(1);
#pragma unroll
        for (int mi = 0; mi < 8; ++mi) {
            acc[mi][0] = __builtin_amdgcn_mfma_f32_16x16x32_bf16(a[mi], b0, acc[mi][0], 0, 0, 0);
            acc[mi][1] = __builtin_amdgcn_mfma_f32_16x16x32_bf16(a[mi], b1, acc[mi][1], 0, 0, 0);
        }
        __builtin_amdgcn_s_setprio(0);
        __builtin_amdgcn_s_barrier();

        // ---- phase 1: quadrant ni 2-3
        b2 = *(const s16x8*)(bB + 2048);
        b3 = *(const s16x8*)(bB + 3072);
        if (t < NT - 3) STAGE_B(t + 3);
        __builtin_amdgcn_s_barrier();
        __builtin_amdgcn_s_setprio(1);
#pragma unroll
        for (int mi = 0; mi < 8; ++mi) {
            acc[mi][2] = __builtin_amdgcn_mfma_f32_16x16x32_bf16(a[mi], b2, acc[mi][2], 0, 0, 0);
            acc[mi][3] = __builtin_amdgcn_mfma_f32_16x16x32_bf16(a[mi], b3, acc[mi][3], 0, 0, 0);
        }
        __builtin_amdgcn_s_setprio(0);
        // counted wait: newest 8 loads = tiles t+2,t+3 in flight; forces t+1 landed
        if (t <= NT - 4)      asm volatile("s_waitcnt vmcnt(8)" ::: "memory");
        else if (t == NT - 3) asm volatile("s_waitcnt vmcnt(4)" ::: "memory");
        else                  asm volatile("s_waitcnt vmcnt(0)" ::: "memory");
        __builtin_amdgcn_s_barrier();
    }

    // epilogue: C/D layout col = lane&15, row = (lane>>4)*4 + reg
    const int rq = (lane >> 4) * 4;
#pragma unroll
    for (int ni = 0; ni < 4; ++ni) {
        int gn = n0 + wn * 64 + ni * 16 + rl;
        float bv = bias[gn];
#pragma unroll
        for (int mi = 0; mi < 8; ++mi) {
            int gm = m0 + wm * 128 + mi * 16 + rq;
#pragma unroll
            for (int r = 0; r < 4; ++r)
                out[(size_t)(gm + r) * OUT_F + gn] = acc[mi][ni][r] + bv;
        }
    }
#undef STAGE_A
#undef STAGE_B
}

extern "C" void kernel_launch(void* const* d_in, const int* in_sizes, int n_in,
                              void* d_out, int out_size, void* d_ws, size_t ws_size,
                              hipStream_t stream) {
    const float* x    = (const float*)d_in[0];
    const int*   qw   = (const int*)d_in[1];
    const float* qs   = (const float*)d_in[2];
    const float* bias = (const float*)d_in[3];
    const float* lA   = (const float*)d_in[4];
    const float* lB   = (const float*)d_in[5];
    float* out = (float*)d_out;

    const int xN = in_sizes[0];          // M * IN_F
    const int M  = xN / IN_F;            // 8192
    const int nmt = M / 256;             // 32 m-tiles

    // workspace: [x_bf16: xN shorts][W_eff: OUT_F*IN_F shorts] ~ 100 MB
    short* xb = (short*)d_ws;
    short* wb = xb + (size_t)xN;

    const int n8 = xN / 8;
    hipLaunchKernelGGL(cvt_x_kernel, dim3(n8 / 256), dim3(256), 0, stream,
                       x, (u16*)xb, n8);
    hipLaunchKernelGGL(build_weff_kernel, dim3((OUT_F * (IN_F / 8)) / 256), dim3(256),
                       0, stream, qw, qs, lA, lB, (u16*)wb);
    hipLaunchKernelGGL(gemm_bt_kernel, dim3(nmt * 16), dim3(512), 0, stream,
                       xb, wb, bias, out, nmt);
}

// Round 3
// 527.620 us; speedup vs baseline: 1.3553x; 1.0770x over previous
//
#include <hip/hip_runtime.h>
#include <hip/hip_bf16.h>
#include <stdint.h>

// QLoRA linear on MI355X (gfx950).
// Decomposition: out = xb@dequant(q,s)^T + bias + 2*(xb@A^T)@B^T
//   prep   : x->bf16, W=bf16(q*s), A->bf16      (one fused streaming kernel)
//   lora_t1: t1 = xb@A^T  [M x 16] bf16         (MFMA, K-split + LDS reduce)
//   gemm   : 256x256 tile, BK=32, 8 waves, 4 LDS bufs, counted vmcnt(8),
//            T2 both-sides swizzle, T5 setprio, T1 XCD swizzle;
//            epilogue adds LoRA via 32 zero-padded 16x16x32 MFMAs + bias.

#define IN_F 4096
#define OUT_F 4096

typedef unsigned short u16;
typedef __attribute__((ext_vector_type(8))) short s16x8;
typedef __attribute__((ext_vector_type(4))) float f32x4;

__device__ inline u16 f2bf(float f) {
    union { float f; uint32_t u; } v; v.f = f;
    uint32_t u = v.u;
    return (u16)((u + 0x7FFFu + ((u >> 16) & 1u)) >> 16);   // RNE fp32->bf16
}

// --------------------------------------------- fused prep: cvt_x | dequant | cvt_A
__global__ __launch_bounds__(256) void prep_kernel(const float* __restrict__ x,
                                                   const int* __restrict__ qw,
                                                   const float* __restrict__ qs,
                                                   const float* __restrict__ lA,
                                                   u16* __restrict__ xb,
                                                   u16* __restrict__ wb,
                                                   u16* __restrict__ Ab,
                                                   int nxblk) {
    const int bid = blockIdx.x;
    if (bid < nxblk) {                                  // x -> bf16 (8 elems/thr)
        int t = bid * 256 + threadIdx.x;
        const float4* src = (const float4*)x + (size_t)t * 2;
        float4 a = src[0], b = src[1];
        union { u16 u[8]; s16x8 v; } o;
        o.u[0] = f2bf(a.x); o.u[1] = f2bf(a.y); o.u[2] = f2bf(a.z); o.u[3] = f2bf(a.w);
        o.u[4] = f2bf(b.x); o.u[5] = f2bf(b.y); o.u[6] = f2bf(b.z); o.u[7] = f2bf(b.w);
        ((s16x8*)xb)[t] = o.v;
    } else if (bid < nxblk + 8192) {                    // W = bf16(q*s)
        int t = (bid - nxblk) * 256 + threadIdx.x;      // OUT_F*IN_F/8 threads
        int o = t >> 9, i0 = (t & 511) << 3;
        float s = qs[o];
        const int4* q4 = (const int4*)(qw + (size_t)o * IN_F + i0);
        int4 qa = q4[0], qb = q4[1];
        union { u16 u[8]; s16x8 v; } ov;
        ov.u[0] = f2bf(qa.x * s); ov.u[1] = f2bf(qa.y * s);
        ov.u[2] = f2bf(qa.z * s); ov.u[3] = f2bf(qa.w * s);
        ov.u[4] = f2bf(qb.x * s); ov.u[5] = f2bf(qb.y * s);
        ov.u[6] = f2bf(qb.z * s); ov.u[7] = f2bf(qb.w * s);
        ((s16x8*)wb)[t] = ov.v;
    } else {                                            // lA -> bf16 (16*4096)
        int t = (bid - nxblk - 8192) * 256 + threadIdx.x;   // 8192 threads
        const float4* src = (const float4*)lA + (size_t)t * 2;
        float4 a = src[0], b = src[1];
        union { u16 u[8]; s16x8 v; } o;
        o.u[0] = f2bf(a.x); o.u[1] = f2bf(a.y); o.u[2] = f2bf(a.z); o.u[3] = f2bf(a.w);
        o.u[4] = f2bf(b.x); o.u[5] = f2bf(b.y); o.u[6] = f2bf(b.z); o.u[7] = f2bf(b.w);
        ((s16x8*)Ab)[t] = o.v;
    }
}

// --------------------------------------------------------- t1 = xb @ Ab^T  [M x 16]
// block: 16 m-rows, 4 waves split K (1024 each), MFMA 16x16x32, LDS reduce.
__global__ __launch_bounds__(256) void lora_t1_kernel(const short* __restrict__ xb,
                                                      const short* __restrict__ Ab,
                                                      u16* __restrict__ t1) {
    __shared__ float red[4][16][16];
    const int tid = threadIdx.x;
    const int w = tid >> 6, lane = tid & 63;
    const int m0 = blockIdx.x * 16;
    const int rsel = lane & 15, koff = (lane >> 4) * 8;

    f32x4 acc = {0.f, 0.f, 0.f, 0.f};
    const short* pa = xb + (size_t)(m0 + rsel) * IN_F + koff;
    const short* pb = Ab + (size_t)rsel * IN_F + koff;
#pragma unroll 4
    for (int kt = w * 1024; kt < (w + 1) * 1024; kt += 32) {
        s16x8 a = *(const s16x8*)(pa + kt);
        s16x8 b = *(const s16x8*)(pb + kt);
        acc = __builtin_amdgcn_mfma_f32_16x16x32_bf16(a, b, acc, 0, 0, 0);
    }
    // C layout: col = lane&15 (r), row = (lane>>4)*4 + reg (m)
#pragma unroll
    for (int r = 0; r < 4; ++r) red[w][(lane >> 4) * 4 + r][lane & 15] = acc[r];
    __syncthreads();
    if (tid < 256) {
        int mr = tid >> 4, c = tid & 15;
        float s = red[0][mr][c] + red[1][mr][c] + red[2][mr][c] + red[3][mr][c];
        t1[(size_t)(m0 + mr) * 16 + c] = f2bf(s);
    }
}

// ---------------------------------------------------------------- bf16 GEMM B^T
// out[m][n] = sum_k xb[m][k]*wb[n][k] + bias[n] + 2*sum_r t1[m][r]*lB[n][r]
#define BK 32
#define NT (IN_F / BK)     // 128 K-tiles

#define GLD16(gp, lp)                                                          \
    __builtin_amdgcn_global_load_lds(                                          \
        (const __attribute__((address_space(1))) void*)(gp),                   \
        (__attribute__((address_space(3))) void*)(lp), 16, 0, 0)

__global__ __launch_bounds__(512, 2) void gemm_bt_kernel(const short* __restrict__ Xb,
                                                         const short* __restrict__ Wb,
                                                         const float* __restrict__ bias,
                                                         const short* __restrict__ t1,
                                                         const float* __restrict__ lB,
                                                         float* __restrict__ out,
                                                         int nmt) {
    __shared__ __align__(16) char smem[131072];

    const int tid  = threadIdx.x;
    const int w    = tid >> 6, lane = tid & 63;
    const int wm   = w >> 2, wn = w & 3;        // 2M x 4N wave grid
    const int rl   = lane & 15;

    // T1: bijective XCD swizzle (nwg % 8 == 0)
    const int nwg = nmt * 16;
    const int cpx = nwg >> 3;
    const int f   = blockIdx.x;
    const int swz = (f & 7) * cpx + (f >> 3);
    const int m0  = (swz >> 4) * 256;
    const int n0  = (swz & 15) * 256;

    // staging: linear LDS dest, inverse-swizzled global source (rule 21)
    const int L0   = w * 1024 + lane * 16;
    const int S0   = L0 ^ (((lane >> 3) & 3) << 4);
    const int srow = S0 >> 6;
    const int scol = (S0 & 63) >> 1;
    const short* pA = Xb + (size_t)(m0 + srow) * IN_F + scol;
    const short* pB = Wb + (size_t)(n0 + srow) * IN_F + scol;
    char* ldsA = (char*)smem;
    char* ldsB = (char*)smem + 65536;
    const int woff = w * 1024;

#define STAGE_A(t) do { int bo_ = ((t) & 3) * 16384 + woff;                    \
        const short* s_ = pA + (size_t)(t) * BK;                               \
        GLD16(s_, ldsA + bo_);                                                 \
        GLD16(s_ + (size_t)128 * IN_F, ldsA + bo_ + 8192); } while (0)
#define STAGE_B(t) do { int bo_ = ((t) & 3) * 16384 + woff;                    \
        const short* s_ = pB + (size_t)(t) * BK;                               \
        GLD16(s_, ldsB + bo_);                                                 \
        GLD16(s_ + (size_t)128 * IN_F, ldsB + bo_ + 8192); } while (0)

    // swizzled ds_read addressing
    const int colpart = ((lane >> 4) * 16) ^ (((rl >> 1) & 3) << 4);
    const int aRow = (wm * 128 + rl) * 64 + colpart;
    const int bRow = (wn * 64 + rl) * 64 + colpart;

    f32x4 acc[8][4];
    f32x4 zero = {0.f, 0.f, 0.f, 0.f};
#pragma unroll
    for (int i = 0; i < 8; ++i)
#pragma unroll
        for (int j = 0; j < 4; ++j) acc[i][j] = zero;

    STAGE_A(0); STAGE_B(0); STAGE_A(1); STAGE_B(1); STAGE_A(2); STAGE_B(2);
    asm volatile("s_waitcnt vmcnt(8)" ::: "memory");
    __builtin_amdgcn_s_barrier();

    for (int t = 0; t < NT; ++t) {
        const char* aB = ldsA + (t & 3) * 16384 + aRow;
        const char* bB = ldsB + (t & 3) * 16384 + bRow;
        s16x8 a[8], b0, b1, b2, b3;

#pragma unroll
        for (int mi = 0; mi < 8; ++mi) a[mi] = *(const s16x8*)(aB + mi * 1024);
        b0 = *(const s16x8*)(bB);
        b1 = *(const s16x8*)(bB + 1024);
        if (t < NT - 3) STAGE_A(t + 3);
        __builtin_amdgcn_s_barrier();
        __builtin_amdgcn_s_setprio(1);
#pragma unroll
        for (int mi = 0; mi < 8; ++mi) {
            acc[mi][0] = __builtin_amdgcn_mfma_f32_16x16x32_bf16(a[mi], b0, acc[mi][0], 0, 0, 0);
            acc[mi][1] = __builtin_amdgcn_mfma_f32_16x16x32_bf16(a[mi], b1, acc[mi][1], 0, 0, 0);
        }
        __builtin_amdgcn_s_setprio(0);
        __builtin_amdgcn_s_barrier();

        b2 = *(const s16x8*)(bB + 2048);
        b3 = *(const s16x8*)(bB + 3072);
        if (t < NT - 3) STAGE_B(t + 3);
        __builtin_amdgcn_s_barrier();
        __builtin_amdgcn_s_setprio(1);
#pragma unroll
        for (int mi = 0; mi < 8; ++mi) {
            acc[mi][2] = __builtin_amdgcn_mfma_f32_16x16x32_bf16(a[mi], b2, acc[mi][2], 0, 0, 0);
            acc[mi][3] = __builtin_amdgcn_mfma_f32_16x16x32_bf16(a[mi], b3, acc[mi][3], 0, 0, 0);
        }
        __builtin_amdgcn_s_setprio(0);
        if (t <= NT - 4)      asm volatile("s_waitcnt vmcnt(8)" ::: "memory");
        else if (t == NT - 3) asm volatile("s_waitcnt vmcnt(4)" ::: "memory");
        else                  asm volatile("s_waitcnt vmcnt(0)" ::: "memory");
        __builtin_amdgcn_s_barrier();
    }

    // ---- epilogue: LoRA rank-16 correction via zero-padded K=32 MFMA ----
    // stage t1 tile [256][40]s (k 0..15 data, 16..31 zero) and 2*lB tile same;
    // 80 B row stride: banks rotate by 20 -> 2-way aliasing (free).
    __syncthreads();
    short* t1b = (short*)smem;            // 20480 B
    short* lbb = (short*)smem + 10240;    // 20480 B
    {
        const int4 z4 = {0, 0, 0, 0};
        if (tid < 256) {
            const int4* src = (const int4*)(t1 + (size_t)(m0 + tid) * 16);
            int4 v0 = src[0], v1 = src[1];
            int4* dst = (int4*)&t1b[tid * 40];
            dst[0] = v0; dst[1] = v1; dst[2] = z4; dst[3] = z4;
        } else {
            int r = tid - 256;
            const float4* src = (const float4*)(lB + (size_t)(n0 + r) * 16);
            float4 b0 = src[0], b1 = src[1], b2 = src[2], b3 = src[3];
            union { u16 u[16]; int4 v[2]; } p;
            p.u[0]  = f2bf(2.f * b0.x); p.u[1]  = f2bf(2.f * b0.y);
            p.u[2]  = f2bf(2.f * b0.z); p.u[3]  = f2bf(2.f * b0.w);
            p.u[4]  = f2bf(2.f * b1.x); p.u[5]  = f2bf(2.f * b1.y);
            p.u[6]  = f2bf(2.f * b1.z); p.u[7]  = f2bf(2.f * b1.w);
            p.u[8]  = f2bf(2.f * b2.x); p.u[9]  = f2bf(2.f * b2.y);
            p.u[10] = f2bf(2.f * b2.z); p.u[11] = f2bf(2.f * b2.w);
            p.u[12] = f2bf(2.f * b3.x); p.u[13] = f2bf(2.f * b3.y);
            p.u[14] = f2bf(2.f * b3.z); p.u[15] = f2bf(2.f * b3.w);
            int4* dst = (int4*)&lbb[r * 40];
            dst[0] = p.v[0]; dst[1] = p.v[1]; dst[2] = z4; dst[3] = z4;
        }
    }
    __syncthreads();
    {
        const int kb = (lane >> 4) * 16;          // byte offset of lane's 8 k-elems
        s16x8 bf2[4];
#pragma unroll
        for (int ni = 0; ni < 4; ++ni)
            bf2[ni] = *(const s16x8*)((const char*)lbb + (wn * 64 + ni * 16 + rl) * 80 + kb);
#pragma unroll
        for (int mi = 0; mi < 8; ++mi) {
            s16x8 af2 = *(const s16x8*)((const char*)t1b + (wm * 128 + mi * 16 + rl) * 80 + kb);
#pragma unroll
            for (int ni = 0; ni < 4; ++ni)
                acc[mi][ni] = __builtin_amdgcn_mfma_f32_16x16x32_bf16(af2, bf2[ni], acc[mi][ni], 0, 0, 0);
        }
    }

    // C-write: col = lane&15, row = (lane>>4)*4 + reg
    const int rq = (lane >> 4) * 4;
#pragma unroll
    for (int ni = 0; ni < 4; ++ni) {
        int gn = n0 + wn * 64 + ni * 16 + rl;
        float bv = bias[gn];
#pragma unroll
        for (int mi = 0; mi < 8; ++mi) {
            int gm = m0 + wm * 128 + mi * 16 + rq;
#pragma unroll
            for (int r = 0; r < 4; ++r)
                out[(size_t)(gm + r) * OUT_F + gn] = acc[mi][ni][r] + bv;
        }
    }
#undef STAGE_A
#undef STAGE_B
}

extern "C" void kernel_launch(void* const* d_in, const int* in_sizes, int n_in,
                              void* d_out, int out_size, void* d_ws, size_t ws_size,
                              hipStream_t stream) {
    const float* x    = (const float*)d_in[0];
    const int*   qw   = (const int*)d_in[1];
    const float* qs   = (const float*)d_in[2];
    const float* bias = (const float*)d_in[3];
    const float* lA   = (const float*)d_in[4];
    const float* lB   = (const float*)d_in[5];
    float* out = (float*)d_out;

    const int xN = in_sizes[0];          // M * IN_F
    const int M  = xN / IN_F;            // 8192
    const int nmt = M / 256;

    // ws layout (shorts): xb[xN] | wb[OUT_F*IN_F] | Ab[16*IN_F] | t1[M*16]
    short* xb = (short*)d_ws;
    short* wb = xb + (size_t)xN;
    short* Ab = wb + (size_t)OUT_F * IN_F;
    short* t1 = Ab + (size_t)16 * IN_F;

    const int nxblk = xN / 8 / 256;
    hipLaunchKernelGGL(prep_kernel, dim3(nxblk + 8192 + 32), dim3(256), 0, stream,
                       x, qw, qs, lA, (u16*)xb, (u16*)wb, (u16*)Ab, nxblk);
    hipLaunchKernelGGL(lora_t1_kernel, dim3(M / 16), dim3(256), 0, stream,
                       xb, Ab, (u16*)t1);
    hipLaunchKernelGGL(gemm_bt_kernel, dim3(nmt * 16), dim3(512), 0, stream,
                       xb, wb, bias, t1, lB, out, nmt);
}